// Round 1
// baseline (362.713 us; speedup 1.0000x reference)
//
#include <hip/hip_runtime.h>
#include <math.h>

#define B_    64
#define S_    4096
#define H_    256
#define SPLIT 16
#define CHUNK (S_ / SPLIT)        // 256 positions per block
#define PPW   (CHUNK / 4)         // 64 positions per wave
#define RECS  272                 // record stride in floats (acc[256], m, l, pad)

// Pass 1: flash-style online softmax over a chunk of S, one partial record per block.
__global__ __launch_bounds__(256) void attn_pass1(
    const float* __restrict__ hidden,   // (B, H)
    const float* __restrict__ enc,      // (B, S, H)
    float* __restrict__ ws)             // (B*SPLIT) records of RECS floats
{
    const int split = blockIdx.x;
    const int b     = blockIdx.y;
    const int tid   = threadIdx.x;
    const int wave  = tid >> 6;
    const int lane  = tid & 63;

    // lane l holds h[b][4l..4l+3]
    const float4 h4 = ((const float4*)(hidden + (size_t)b * H_))[lane];

    const int s0 = split * CHUNK + wave * PPW;
    const float4* ep = (const float4*)(enc + ((size_t)b * S_ + s0) * H_) + lane;

    float  m = -INFINITY;
    float  l = 0.f;
    float4 acc = {0.f, 0.f, 0.f, 0.f};

    #pragma unroll 4
    for (int i = 0; i < PPW; ++i) {
        float4 ev = ep[(size_t)i * (H_ / 4)];   // wave reads 1 KiB, coalesced
        float e = ev.x * h4.x + ev.y * h4.y + ev.z * h4.z + ev.w * h4.w;
        #pragma unroll
        for (int off = 32; off > 0; off >>= 1)
            e += __shfl_xor(e, off, 64);        // all 64 lanes get full dot
        float mn = fmaxf(m, e);
        float sc = __expf(m - mn);              // first iter: exp(-inf)=0
        float w  = __expf(e - mn);
        l = l * sc + w;
        acc.x = acc.x * sc + w * ev.x;
        acc.y = acc.y * sc + w * ev.y;
        acc.z = acc.z * sc + w * ev.z;
        acc.w = acc.w * sc + w * ev.w;
        m = mn;
    }

    // merge the 4 waves' partials via LDS
    __shared__ float4 s_acc[4][64];
    __shared__ float  s_m[4], s_l[4];
    if (lane == 0) { s_m[wave] = m; s_l[wave] = l; }
    s_acc[wave][lane] = acc;
    __syncthreads();

    const float M  = fmaxf(fmaxf(s_m[0], s_m[1]), fmaxf(s_m[2], s_m[3]));
    const float f0 = __expf(s_m[0] - M);
    const float f1 = __expf(s_m[1] - M);
    const float f2 = __expf(s_m[2] - M);
    const float f3 = __expf(s_m[3] - M);
    const float ltot = f0 * s_l[0] + f1 * s_l[1] + f2 * s_l[2] + f3 * s_l[3];

    const float* a0 = (const float*)&s_acc[0][0];
    const float* a1 = (const float*)&s_acc[1][0];
    const float* a2 = (const float*)&s_acc[2][0];
    const float* a3 = (const float*)&s_acc[3][0];
    const float v = f0 * a0[tid] + f1 * a1[tid] + f2 * a2[tid] + f3 * a3[tid];

    float* rec = ws + (size_t)(b * SPLIT + split) * RECS;
    rec[tid] = v;
    if (tid == 0) { rec[256] = M; rec[257] = ltot; }
}

// Pass 2: merge SPLIT partials per batch, normalize, write context.
__global__ __launch_bounds__(256) void attn_pass2(
    const float* __restrict__ ws,
    float* __restrict__ out)            // (B, H)
{
    const int b   = blockIdx.x;
    const int tid = threadIdx.x;

    __shared__ float s_m[SPLIT], s_l[SPLIT];
    if (tid < SPLIT) {
        const float* rec = ws + (size_t)(b * SPLIT + tid) * RECS;
        s_m[tid] = rec[256];
        s_l[tid] = rec[257];
    }
    __syncthreads();

    float M = -INFINITY;
    #pragma unroll
    for (int i = 0; i < SPLIT; ++i) M = fmaxf(M, s_m[i]);

    float denom = 0.f;
    float v = 0.f;
    #pragma unroll
    for (int i = 0; i < SPLIT; ++i) {
        const float f = __expf(s_m[i] - M);
        denom += f * s_l[i];
        v += f * ws[(size_t)(b * SPLIT + i) * RECS + tid];
    }
    out[(size_t)b * H_ + tid] = v / denom;
}

extern "C" void kernel_launch(void* const* d_in, const int* in_sizes, int n_in,
                              void* d_out, int out_size, void* d_ws, size_t ws_size,
                              hipStream_t stream) {
    const float* hidden = (const float*)d_in[0];   // (1, B, H) fp32
    const float* enc    = (const float*)d_in[1];   // (B, S, H) fp32
    float* out = (float*)d_out;                    // (B, H) fp32
    float* ws  = (float*)d_ws;                     // >= B*SPLIT*RECS*4 = ~1.1 MB

    attn_pass1<<<dim3(SPLIT, B_), 256, 0, stream>>>(hidden, enc, ws);
    attn_pass2<<<B_, 256, 0, stream>>>(ws, out);
}

// Round 2
// 357.979 us; speedup vs baseline: 1.0132x; 1.0132x over previous
//
#include <hip/hip_runtime.h>
#include <math.h>

#define B_     64
#define S_     4096
#define H_     256
#define SPLIT  32
#define CHUNK  (S_ / SPLIT)      // 128 positions per block
#define PPW    (CHUNK / 4)       // 32 positions per wave
#define ROUNDS (PPW / 4)         // 8 rounds; 4 positions per round (one per 16-lane group)
#define RECS   264               // record stride in floats (acc[256], m, l, pad)

// Pass 1: flash-style online softmax. Each wave handles 4 positions per round:
// lane group g (16 lanes) owns position s+g; lane i owns H float4-slices {i+16k}.
// Cross-lane reduce is 4 shuffle stages shared by 4 positions (1 shuffle/pos).
__global__ __launch_bounds__(256) void attn_pass1(
    const float* __restrict__ hidden,   // (B, H)
    const float* __restrict__ enc,      // (B, S, H)
    float* __restrict__ ws)             // (B*SPLIT) records of RECS floats
{
    const int split = blockIdx.x;
    const int b     = blockIdx.y;
    const int tid   = threadIdx.x;
    const int wave  = tid >> 6;
    const int lane  = tid & 63;
    const int g     = lane >> 4;        // position-within-round
    const int i     = lane & 15;        // H-slice index

    // h fragments: float4 indices i + 16k, k=0..3
    const float4* hrow = (const float4*)(hidden + (size_t)b * H_);
    float4 h4[4];
    #pragma unroll
    for (int k = 0; k < 4; ++k) h4[k] = hrow[i + 16 * k];

    // this lane's row for round r: p(r) = split*CHUNK + wave*PPW + 4r + g
    const int p0 = split * CHUNK + wave * PPW + g;
    const float4* erow = (const float4*)(enc + ((size_t)b * S_ + p0) * H_);

    float  m = -INFINITY, l = 0.f;
    float4 acc[4] = {{0,0,0,0},{0,0,0,0},{0,0,0,0},{0,0,0,0}};

    // prefetch round 0
    float4 ev[4];
    #pragma unroll
    for (int k = 0; k < 4; ++k) ev[k] = erow[i + 16 * k];

    for (int r = 0; r < ROUNDS; ++r) {
        float4 nv[4];
        const bool more = (r + 1 < ROUNDS);
        if (more) {
            const float4* nrow = erow + (size_t)(r + 1) * 4 * (H_ / 4);
            #pragma unroll
            for (int k = 0; k < 4; ++k) nv[k] = nrow[i + 16 * k];
        }
        // partial dot over this lane's 16 floats
        float e = 0.f;
        #pragma unroll
        for (int k = 0; k < 4; ++k) {
            e = fmaf(ev[k].x, h4[k].x, e);
            e = fmaf(ev[k].y, h4[k].y, e);
            e = fmaf(ev[k].z, h4[k].z, e);
            e = fmaf(ev[k].w, h4[k].w, e);
        }
        // reduce across the 16-lane group (xor 1,2,4,8 stay within group)
        e += __shfl_xor(e, 1);
        e += __shfl_xor(e, 2);
        e += __shfl_xor(e, 4);
        e += __shfl_xor(e, 8);
        // online softmax update (independent per group)
        const float mn = fmaxf(m, e);
        const float sc = __expf(m - mn);    // first round: exp(-inf)=0
        const float w  = __expf(e - mn);
        l = l * sc + w;
        #pragma unroll
        for (int k = 0; k < 4; ++k) {
            acc[k].x = acc[k].x * sc + w * ev[k].x;
            acc[k].y = acc[k].y * sc + w * ev[k].y;
            acc[k].z = acc[k].z * sc + w * ev[k].z;
            acc[k].w = acc[k].w * sc + w * ev[k].w;
        }
        m = mn;
        if (more) {
            #pragma unroll
            for (int k = 0; k < 4; ++k) ev[k] = nv[k];
        }
    }

    // ---- merge the 4 groups within the wave (butterfly over xor 16, 32) ----
    float M = m;
    M = fmaxf(M, __shfl_xor(M, 16));
    M = fmaxf(M, __shfl_xor(M, 32));
    const float f = __expf(m - M);
    float lw = l * f;
    lw += __shfl_xor(lw, 16);
    lw += __shfl_xor(lw, 32);
    #pragma unroll
    for (int k = 0; k < 4; ++k) {
        acc[k].x *= f; acc[k].y *= f; acc[k].z *= f; acc[k].w *= f;
        acc[k].x += __shfl_xor(acc[k].x, 16);
        acc[k].y += __shfl_xor(acc[k].y, 16);
        acc[k].z += __shfl_xor(acc[k].z, 16);
        acc[k].w += __shfl_xor(acc[k].w, 16);
        acc[k].x += __shfl_xor(acc[k].x, 32);
        acc[k].y += __shfl_xor(acc[k].y, 32);
        acc[k].z += __shfl_xor(acc[k].z, 32);
        acc[k].w += __shfl_xor(acc[k].w, 32);
    }
    // now every lane holds the wave's full context partial for slices {i+16k}

    // ---- merge the 4 waves via LDS ----
    __shared__ float s_ctx[4][H_];
    __shared__ float s_m[4], s_l[4];
    if (lane < 16) {
        float4* dst = (float4*)s_ctx[wave];
        #pragma unroll
        for (int k = 0; k < 4; ++k) dst[i + 16 * k] = acc[k];
    }
    if (lane == 0) { s_m[wave] = M; s_l[wave] = lw; }
    __syncthreads();

    const float MM = fmaxf(fmaxf(s_m[0], s_m[1]), fmaxf(s_m[2], s_m[3]));
    const float f0 = __expf(s_m[0] - MM);
    const float f1 = __expf(s_m[1] - MM);
    const float f2 = __expf(s_m[2] - MM);
    const float f3 = __expf(s_m[3] - MM);
    const float ltot = f0 * s_l[0] + f1 * s_l[1] + f2 * s_l[2] + f3 * s_l[3];
    const float v = f0 * s_ctx[0][tid] + f1 * s_ctx[1][tid]
                  + f2 * s_ctx[2][tid] + f3 * s_ctx[3][tid];

    float* rec = ws + (size_t)(b * SPLIT + split) * RECS;
    rec[tid] = v;
    if (tid == 0) { rec[256] = MM; rec[257] = ltot; }
}

// Pass 2: merge SPLIT partials per batch, normalize, write context.
__global__ __launch_bounds__(256) void attn_pass2(
    const float* __restrict__ ws,
    float* __restrict__ out)            // (B, H)
{
    const int b   = blockIdx.x;
    const int tid = threadIdx.x;

    __shared__ float s_m[SPLIT], s_l[SPLIT];
    if (tid < SPLIT) {
        const float* rec = ws + (size_t)(b * SPLIT + tid) * RECS;
        s_m[tid] = rec[256];
        s_l[tid] = rec[257];
    }
    __syncthreads();

    float M = -INFINITY;
    #pragma unroll
    for (int i = 0; i < SPLIT; ++i) M = fmaxf(M, s_m[i]);

    float denom = 0.f;
    float v = 0.f;
    #pragma unroll
    for (int i = 0; i < SPLIT; ++i) {
        const float f = __expf(s_m[i] - M);
        denom += f * s_l[i];
        v += f * ws[(size_t)(b * SPLIT + i) * RECS + tid];
    }
    out[(size_t)b * H_ + tid] = v / denom;
}

extern "C" void kernel_launch(void* const* d_in, const int* in_sizes, int n_in,
                              void* d_out, int out_size, void* d_ws, size_t ws_size,
                              hipStream_t stream) {
    const float* hidden = (const float*)d_in[0];   // (1, B, H) fp32
    const float* enc    = (const float*)d_in[1];   // (B, S, H) fp32
    float* out = (float*)d_out;                    // (B, H) fp32
    float* ws  = (float*)d_ws;                     // uses ~2.2 MB

    attn_pass1<<<dim3(SPLIT, B_), 256, 0, stream>>>(hidden, enc, ws);
    attn_pass2<<<B_, 256, 0, stream>>>(ws, out);
}